// Round 4
// baseline (172.641 us; speedup 1.0000x reference)
//
#include <hip/hip_runtime.h>
#include <math.h>

#define EDIM 128
#define NHEAD 16
#define HDIM 8
#define SEQ 2048
#define BATCH 4
#define NROW (BATCH*SEQ)            // 8192
// -scale*log2(e): folded into Q at projection time so sigmoid = rcp(1+exp2(dot))
#define QNEG (-0.35355339059327373f * 1.4426950408889634f)

#if __has_builtin(__builtin_amdgcn_exp2f)
#define EXP2F(x) __builtin_amdgcn_exp2f(x)
#else
#define EXP2F(x) exp2f(x)
#endif
#define RCPF(x) __builtin_amdgcn_rcpf(x)

typedef __attribute__((ext_vector_type(8))) short short8v;
typedef __attribute__((ext_vector_type(4))) short short4v;
typedef __attribute__((ext_vector_type(4))) float float4v;

union U16x8 { uint4 u; short8v s; };
union U16x4 { uint2 u; short4v s; };

#if __has_builtin(__builtin_amdgcn_mfma_f32_16x16x16bf16_1k)
#define MFMA_PV(a,b,c) __builtin_amdgcn_mfma_f32_16x16x16bf16_1k(a,b,c,0,0,0)
#else
static __device__ __forceinline__ float4v mfma_pv_asm(short4v a, short4v b, float4v c) {
  float4v d;
  asm("v_mfma_f32_16x16x16_bf16 %0, %1, %2, %3" : "=v"(d) : "v"(a), "v"(b), "v"(c));
  return d;
}
#define MFMA_PV(a,b,c) mfma_pv_asm(a,b,c)
#endif

// pack two floats to bf16x2, round-to-nearest-even (values finite)
__device__ __forceinline__ unsigned pk_bf16(float a, float b) {
  unsigned ua = __float_as_uint(a), ub = __float_as_uint(b);
  unsigned lo = (ua + 0x7fffu + ((ua >> 16) & 1u)) >> 16;
  unsigned hi = (ub + 0x7fffu + ((ub >> 16) & 1u)) & 0xffff0000u;
  return lo | hi;
}

// ---------------------------------------------------------------------------
// out = X @ W^T + b reading W DIRECTLY (no pre-transpose kernel).
// Key identity: the inner loop needs WT[4ib+r][col0+c] = W[col0+c][4ib+r],
// i.e. a contiguous float4 of W's row (col0+c): wc = W + (col0+c)*128 + 4ib.
// Same FMA count, bit-identical products/order vs the WT version. Per-iter
// the block touches a hot 16KB line-set of W -> L1-resident after warmup.
// 32 rows x 128 cols per block.
// MODE 0: Q scaled by QNEG -> bf16 [bh][s][8]
// MODE 1: K -> bf16 [bh][s][8]  (coalesced uint2 stores)
// MODE 2: V -> bf16 TILE-BLOCKED TRANSPOSE Vt[bh][t=s>>4][d][si=s&15]
//         via LDS bounce (contiguous 256B per k-tile for attn's dwordx2 load)
// MODE 3: fp32 row-major [rows][128] (final output)
// ---------------------------------------------------------------------------
template<int MODE>
__device__ __forceinline__
void proj_body(const float* __restrict__ X, const float* __restrict__ W,
               const float* __restrict__ bias, void* __restrict__ out)
{
  __shared__ float xs[32][EDIM];                  // 16 KB (reused as vs in MODE 2)
  const int tid = threadIdx.x;
  const int row0 = blockIdx.x * 32;

  const float4* src = (const float4*)(X + row0 * EDIM);
  float4* dst = (float4*)(&xs[0][0]);
  #pragma unroll
  for (int t = 0; t < 4; ++t) dst[tid + t * 256] = src[tid + t * 256];
  __syncthreads();

  const int tc = tid & 31;
  const int tr = tid >> 5;                        // 0..7 (4 rows each)
  const int col0 = tc * 4;

  float acc[4][4];
  #pragma unroll
  for (int r = 0; r < 4; ++r)
    #pragma unroll
    for (int c = 0; c < 4; ++c) acc[r][c] = 0.f;

  #pragma unroll 2
  for (int ib = 0; ib < EDIM / 4; ++ib) {
    const float4 wc0 = *(const float4*)(W + (col0 + 0) * EDIM + 4 * ib);
    const float4 wc1 = *(const float4*)(W + (col0 + 1) * EDIM + 4 * ib);
    const float4 wc2 = *(const float4*)(W + (col0 + 2) * EDIM + 4 * ib);
    const float4 wc3 = *(const float4*)(W + (col0 + 3) * EDIM + 4 * ib);
    #pragma unroll
    for (int r = 0; r < 4; ++r) {
      const float4 x4 = *(const float4*)(&xs[tr * 4 + r][ib * 4]);  // b128 broadcast
      acc[r][0] += x4.x * wc0.x + x4.y * wc0.y + x4.z * wc0.z + x4.w * wc0.w;
      acc[r][1] += x4.x * wc1.x + x4.y * wc1.y + x4.z * wc1.z + x4.w * wc1.w;
      acc[r][2] += x4.x * wc2.x + x4.y * wc2.y + x4.z * wc2.z + x4.w * wc2.w;
      acc[r][3] += x4.x * wc3.x + x4.y * wc3.y + x4.z * wc3.z + x4.w * wc3.w;
    }
  }

  const float4 b4 = *(const float4*)(bias + col0);

  if (MODE == 2) {
    // --- V tile-blocked transpose: acc -> bf16 in LDS [s(32)][col(128)],
    // then readout to Vt[bh][t][d][si]. Block covers exactly 2 k-tiles. ---
    float4 os[4];
    #pragma unroll
    for (int r = 0; r < 4; ++r)
      os[r] = make_float4(acc[r][0] + b4.x, acc[r][1] + b4.y,
                          acc[r][2] + b4.z, acc[r][3] + b4.w);
    __syncthreads();                              // all lanes done reading xs
    unsigned short* vs = (unsigned short*)&xs[0][0];   // [32][128] u16 = 8 KB
    #pragma unroll
    for (int r = 0; r < 4; ++r) {
      uint2 p;
      p.x = pk_bf16(os[r].x, os[r].y);
      p.y = pk_bf16(os[r].z, os[r].w);
      *(uint2*)(vs + (tr * 4 + r) * EDIM + col0) = p;
    }
    __syncthreads();
    // readout: thread -> (row = col index h*8+d, tile = which 16-s half)
    const int row  = tid & 127;                   // h*8 + d
    const int tile = tid >> 7;                    // 0/1
    const unsigned short* sp = vs + (tile * 16) * EDIM + row;
    unsigned wb[8];
    #pragma unroll
    for (int i = 0; i < 8; ++i)
      wb[i] = (unsigned)sp[(2 * i) * EDIM] | ((unsigned)sp[(2 * i + 1) * EDIM] << 16);
    const int b_ = row0 >> 11, s0 = row0 & (SEQ - 1);
    const int h = row >> 3, dd = row & 7;
    const int bh = b_ * NHEAD + h;
    const int tg = (s0 >> 4) + tile;              // global k-tile index
    unsigned short* dp = (unsigned short*)out
        + (size_t)bh * (SEQ * HDIM) + tg * 128 + dd * 16;
    *(uint4*)dp       = make_uint4(wb[0], wb[1], wb[2], wb[3]);   // si 0..7
    *(uint4*)(dp + 8) = make_uint4(wb[4], wb[5], wb[6], wb[7]);   // si 8..15
    return;
  }

  #pragma unroll
  for (int r = 0; r < 4; ++r) {
    const int grow = row0 + tr * 4 + r;
    const float4 o = make_float4(acc[r][0] + b4.x, acc[r][1] + b4.y,
                                 acc[r][2] + b4.z, acc[r][3] + b4.w);
    if (MODE == 3) {
      *(float4*)((float*)out + (size_t)grow * EDIM + col0) = o;
    } else {
      const int b = grow >> 11, s = grow & (SEQ - 1);
      const int h = col0 >> 3, d0 = col0 & 7;     // d0 in {0,4}
      const size_t bhs = (size_t)(b * NHEAD + h) * SEQ + s;
      uint2 p;
      if (MODE == 0) {
        p.x = pk_bf16(o.x * QNEG, o.y * QNEG);
        p.y = pk_bf16(o.z * QNEG, o.w * QNEG);
      } else {
        p.x = pk_bf16(o.x, o.y);
        p.y = pk_bf16(o.z, o.w);
      }
      *(uint2*)((unsigned*)out + bhs * 4 + (d0 >> 1)) = p;
    }
  }
}

__global__ __launch_bounds__(256)
void qkv_kernel(const float* __restrict__ X,
                const float* __restrict__ Wq, const float* __restrict__ Wk,
                const float* __restrict__ Wv,
                const float* __restrict__ bq, const float* __restrict__ bk,
                const float* __restrict__ bv,
                unsigned* __restrict__ qb, unsigned* __restrict__ kb,
                unsigned* __restrict__ vb)
{
  const int m = blockIdx.y;
  if (m == 0)      proj_body<0>(X, Wq, bq, (void*)qb);
  else if (m == 1) proj_body<1>(X, Wk, bk, (void*)kb);
  else             proj_body<2>(X, Wv, bv, (void*)vb);
}

__global__ __launch_bounds__(256)
void oproj_kernel(const float* __restrict__ A, const float* __restrict__ Wo,
                  const float* __restrict__ bo, float* __restrict__ out)
{
  proj_body<3>(A, Wo, bo, (void*)out);
}

// ---------------------------------------------------------------------------
// One 16q x 16k MFMA step.  (round-0 verified sigmoid path)
// S^T = mfma_16x16x32_bf16(A=K-rows, B=Q-frag) -> C[key][q]. Sigmoid
// elementwise; C-register reinterpreted as A-operand of mfma_16x16x16 gives
// the UN-transposed P, so out[q][d] = mfma(A=P, B=V-frag, acc). V-frag col 8
// is forced to 1.0 so acc col 8 accumulates the denominator.
// ---------------------------------------------------------------------------
template<bool DIAG>
__device__ __forceinline__
float4v attn_step(short8v kf, short8v qf, short4v vf, float4v acc,
                  int laneq, int quad)
{
  const float4v z = {0.f, 0.f, 0.f, 0.f};
  float4v st = __builtin_amdgcn_mfma_f32_16x16x32_bf16(kf, qf, z, 0, 0, 0);
  unsigned rb[4];
  #pragma unroll
  for (int r = 0; r < 4; ++r) {
    float s = RCPF(1.f + EXP2F(st[r]));           // Q carries -scale*log2e
    if (DIAG) s = (4 * quad + r <= laneq) ? s : 0.f;  // exact: sigma(-1e9)==0
    rb[r] = __float_as_uint(s) + 0x8000u;         // round-half-up to bf16
  }
  U16x4 p;
  p.u.x = __builtin_amdgcn_perm(rb[1], rb[0], 0x07060302u);
  p.u.y = __builtin_amdgcn_perm(rb[3], rb[2], 0x07060302u);
  return MFMA_PV(p.s, vf, acc);                   // A = P[q][k], B = V[k][d]
}

// V-frag loader from tile-blocked Vt[bh][t][d][si]: ONE dwordx2 from a
// contiguous 256B tile block. lanes laneq==8 -> bf16 1.0 (denominator col).
__device__ __forceinline__
short4v load_vfrag(const unsigned short* __restrict__ Vtbh, int t,
                   int quad, int d, bool is8)
{
  const unsigned short* p = Vtbh + t * 128 + d * 16 + 4 * quad;
  const uint2 v = *(const uint2*)p;
  U16x4 vf;
  vf.u.x = is8 ? 0x3F803F80u : v.x;
  vf.u.y = is8 ? 0x3F803F80u : v.y;
  return vf.s;
}

// epilogue: den = acc col 8; normalize and store rows of tile T
__device__ __forceinline__
void epilogue(float4v acc, int T, int bh, int laneq, int quad,
              float* __restrict__ out)
{
  const int b_ = bh >> 4, h = bh & 15;
  const int pidx = (quad * 16 + 8) << 2;          // lane holding col 8
  #pragma unroll
  for (int r = 0; r < 4; ++r) {
    const float den = __int_as_float(
        __builtin_amdgcn_ds_bpermute(pidx, __float_as_int(acc[r])));
    const float val = acc[r] * RCPF(den);         // den > 0
    const int row = 16 * T + 4 * quad + r;
    if (laneq < 8)
      out[(size_t)(b_ * SEQ + row) * EDIM + h * HDIM + laneq] = val;
  }
}

// ---------------------------------------------------------------------------
// Causal sigmoid-attention v11: v8 split-K x2 fold-pair schedule, with
// dwordx2 V-frag loads from tile-blocked Vt (contiguous 256B per tile).
// blockIdx low 6 bits = bh -> XCD = bh%8 (L2 locality).
// ---------------------------------------------------------------------------
__global__ __launch_bounds__(128, 8)
void attn_kernel(const unsigned* __restrict__ Qb, const unsigned* __restrict__ Kb,
                 const unsigned* __restrict__ Vb, float* __restrict__ out)
{
  __shared__ float cmb[2][64][4];                 // 2 KB

  const int bh    = blockIdx.x & 63;
  const int g     = blockIdx.x >> 6;              // 0..63
  const int w     = threadIdx.x >> 6;
  const int lane  = threadIdx.x & 63;
  const int laneq = lane & 15;
  const int quad  = lane >> 4;
  const int L = g, H = 127 - g;
  const int mL = (L + 1) >> 1, mH = (H + 1) >> 1;
  const int d   = laneq & 7;
  const bool is8 = (laneq == 8);

  const uint4* Kg = (const uint4*)Kb + (size_t)bh * 2048;
  const uint4* Qg = (const uint4*)Qb + (size_t)bh * 2048;
  const unsigned short* Vtbh = (const unsigned short*)Vb + (size_t)bh * SEQ * HDIM;

  // Q B-frags: lanes<16 hold the 8-dim row in quad 0 (k=0..7); zero others
  U16x8 qfl, qfh;
  {
    const uint4 rl = Qg[16 * L + laneq];
    const uint4 rh = Qg[16 * H + laneq];
    qfl.u = (lane < 16) ? rl : make_uint4(0u, 0u, 0u, 0u);
    qfh.u = (lane < 16) ? rh : make_uint4(0u, 0u, 0u, 0u);
  }

  float4v accL = {0.f, 0.f, 0.f, 0.f};
  float4v accH = {0.f, 0.f, 0.f, 0.f};

  if (w == 0) {
    // k-tiles [0,mL) dual (L+H), [mL,mH) H-only; no diags; prefetch 1 deep
    U16x8 kf; kf.u = Kg[laneq];
    short4v vf = load_vfrag(Vtbh, 0, quad, d, is8);
    #pragma unroll 2
    for (int t = 0; t < mH; ++t) {
      U16x8 kn; kn.u = Kg[16 * (t + 1) + laneq];  // t+1 <= mH <= 64: in-bounds
      short4v vn = load_vfrag(Vtbh, t + 1, quad, d, is8);
      if (t < mL) accL = attn_step<false>(kf.s, qfl.s, vf, accL, laneq, quad);
      accH = attn_step<false>(kf.s, qfh.s, vf, accH, laneq, quad);
      kf = kn; vf = vn;
    }
  } else {
    // L segment: [mL, L], diag at L
    U16x8 kf; kf.u = Kg[16 * mL + laneq];
    short4v vf = load_vfrag(Vtbh, mL, quad, d, is8);
    #pragma unroll 2
    for (int t = mL; t < L; ++t) {
      U16x8 kn; kn.u = Kg[16 * (t + 1) + laneq];
      short4v vn = load_vfrag(Vtbh, t + 1, quad, d, is8);
      accL = attn_step<false>(kf.s, qfl.s, vf, accL, laneq, quad);
      kf = kn; vf = vn;
    }
    accL = attn_step<true>(kf.s, qfl.s, vf, accL, laneq, quad);
    // H segment: [mH, H], diag at H
    kf.u = Kg[16 * mH + laneq];
    vf = load_vfrag(Vtbh, mH, quad, d, is8);
    #pragma unroll 2
    for (int t = mH; t < H; ++t) {
      U16x8 kn; kn.u = Kg[16 * (t + 1) + laneq];  // t+1 <= H = 127: in-bounds
      short4v vn = load_vfrag(Vtbh, t + 1, quad, d, is8);
      accH = attn_step<false>(kf.s, qfh.s, vf, accH, laneq, quad);
      kf = kn; vf = vn;
    }
    accH = attn_step<true>(kf.s, qfh.s, vf, accH, laneq, quad);

    *(float4*)&cmb[0][lane][0] = make_float4(accL[0], accL[1], accL[2], accL[3]);
    *(float4*)&cmb[1][lane][0] = make_float4(accH[0], accH[1], accH[2], accH[3]);
  }
  __syncthreads();

  if (w == 0) {
    const float4 pL = *(const float4*)&cmb[0][lane][0];
    const float4 pH = *(const float4*)&cmb[1][lane][0];
    accL[0] += pL.x; accL[1] += pL.y; accL[2] += pL.z; accL[3] += pL.w;
    accH[0] += pH.x; accH[1] += pH.y; accH[2] += pH.z; accH[3] += pH.w;
    epilogue(accL, L, bh, laneq, quad, out);
    epilogue(accH, H, bh, laneq, quad, out);
  }
}

// ---------------------------------------------------------------------------
extern "C" void kernel_launch(void* const* d_in, const int* in_sizes, int n_in,
                              void* d_out, int out_size, void* d_ws, size_t ws_size,
                              hipStream_t stream)
{
  const float* x  = (const float*)d_in[0];
  const float* Wq = (const float*)d_in[1];
  const float* bq = (const float*)d_in[2];
  const float* Wk = (const float*)d_in[3];
  const float* bk = (const float*)d_in[4];
  const float* Wv = (const float*)d_in[5];
  const float* bv = (const float*)d_in[6];
  const float* Wo = (const float*)d_in[7];
  const float* bo = (const float*)d_in[8];

  float* ws = (float*)d_ws;
  // layout: (unused 65536 f, was WT) | attn 1048576 f | Qb, Kb, Vt 524288 dw
  float*    attn = ws + 65536;
  unsigned* Qb   = (unsigned*)(ws + 65536 + 1048576);
  unsigned* Kb   = Qb + (size_t)524288;
  unsigned* Vb   = Kb + (size_t)524288;

  qkv_kernel<<<dim3(NROW / 32, 3), 256, 0, stream>>>(x, Wq, Wk, Wv, bq, bk, bv,
                                                     Qb, Kb, Vb);
  attn_kernel<<<dim3(4096), 128, 0, stream>>>(Qb, Kb, Vb, attn);
  oproj_kernel<<<dim3(NROW / 32), 256, 0, stream>>>(attn, Wo, bo, (float*)d_out);
}